// Round 1
// baseline (201.379 us; speedup 1.0000x reference)
//
#include <hip/hip_runtime.h>
#include <hip/hip_bf16.h>

#define E 32768
#define DA 1024

// ---------------------------------------------------------------------------
// Kernel 1: per-row edge scores. One wave (64 lanes) per row.
// score[e] = ampli * sum_d  s*f(s),  s = x[d]*W[e,d]
// ---------------------------------------------------------------------------
__global__ __launch_bounds__(256) void score_kernel(
    const float* __restrict__ x,
    const float* __restrict__ ampli,
    const float* __restrict__ W,
    const int*   __restrict__ nid,
    float*       __restrict__ scores)
{
    __shared__ float xs[DA];
    // Stage x into LDS: 256 threads x one float4 = 1024 floats.
    reinterpret_cast<float4*>(xs)[threadIdx.x] =
        reinterpret_cast<const float4*>(x)[threadIdx.x];
    __syncthreads();

    const int wave = threadIdx.x >> 6;
    const int lane = threadIdx.x & 63;
    const int row  = blockIdx.x * 4 + wave;

    const float a    = ampli[0];
    const int   f_id = nid[row];
    const float* Wr  = W + (size_t)row * DA;

    float acc = 0.f;
    #pragma unroll
    for (int k = 0; k < 4; ++k) {
        const int idx = k * 256 + lane * 4;
        const float4 w4 = *reinterpret_cast<const float4*>(Wr + idx);
        const float4 x4 = *reinterpret_cast<const float4*>(xs + idx);
        float sv[4] = { x4.x * w4.x, x4.y * w4.y, x4.z * w4.z, x4.w * w4.w };

        if (f_id == 0) {            // sigmoid: s * 1/(1+e^{-s})
            #pragma unroll
            for (int j = 0; j < 4; ++j)
                acc += sv[j] / (1.f + __expf(-sv[j]));
        } else if (f_id == 1) {     // tanh: s * (1 - 2/(e^{2s}+1))
            #pragma unroll
            for (int j = 0; j < 4; ++j) {
                const float e = __expf(2.f * sv[j]);
                acc += sv[j] * (1.f - 2.f / (e + 1.f));
            }
        } else {                    // relu: s * max(s,0) = s^2 if s>0
            #pragma unroll
            for (int j = 0; j < 4; ++j)
                acc += sv[j] > 0.f ? sv[j] * sv[j] : 0.f;
        }
    }

    // Wave-64 butterfly reduction.
    #pragma unroll
    for (int off = 32; off > 0; off >>= 1)
        acc += __shfl_xor(acc, off, 64);

    if (lane == 0)
        scores[row] = acc * a;
}

// ---------------------------------------------------------------------------
// Kernel 2: softmax over E=32768 scores. One block of 1024 threads,
// 32 values per thread, held in registers.
// ---------------------------------------------------------------------------
__global__ __launch_bounds__(1024) void softmax_kernel(
    const float* __restrict__ scores,
    float*       __restrict__ out)
{
    __shared__ float red[16];
    const int tid  = threadIdx.x;
    const int wid  = tid >> 6;
    const int lane = tid & 63;

    float v[32];
    float m = -__builtin_inff();
    #pragma unroll
    for (int k = 0; k < 8; ++k) {
        const float4 t = reinterpret_cast<const float4*>(scores)[k * 1024 + tid];
        v[k*4+0] = t.x; v[k*4+1] = t.y; v[k*4+2] = t.z; v[k*4+3] = t.w;
        m = fmaxf(m, fmaxf(fmaxf(t.x, t.y), fmaxf(t.z, t.w)));
    }

    // wave-level max
    #pragma unroll
    for (int off = 32; off > 0; off >>= 1)
        m = fmaxf(m, __shfl_xor(m, off, 64));
    if (lane == 0) red[wid] = m;
    __syncthreads();

    float bm = red[0];
    #pragma unroll
    for (int i = 1; i < 16; ++i) bm = fmaxf(bm, red[i]);
    __syncthreads();   // everyone done reading red before reuse

    float sum = 0.f;
    #pragma unroll
    for (int j = 0; j < 32; ++j) {
        v[j] = __expf(v[j] - bm);
        sum += v[j];
    }
    #pragma unroll
    for (int off = 32; off > 0; off >>= 1)
        sum += __shfl_xor(sum, off, 64);
    if (lane == 0) red[wid] = sum;
    __syncthreads();

    float total = 0.f;
    #pragma unroll
    for (int i = 0; i < 16; ++i) total += red[i];
    const float inv = 1.f / total;

    #pragma unroll
    for (int k = 0; k < 8; ++k) {
        float4 t;
        t.x = v[k*4+0] * inv; t.y = v[k*4+1] * inv;
        t.z = v[k*4+2] * inv; t.w = v[k*4+3] * inv;
        reinterpret_cast<float4*>(out)[k * 1024 + tid] = t;
    }
}

// ---------------------------------------------------------------------------
extern "C" void kernel_launch(void* const* d_in, const int* in_sizes, int n_in,
                              void* d_out, int out_size, void* d_ws, size_t ws_size,
                              hipStream_t stream) {
    const float* x     = (const float*)d_in[0];
    const float* ampli = (const float*)d_in[1];
    const float* W     = (const float*)d_in[2];
    const int*   nid   = (const int*)d_in[3];
    float* out    = (float*)d_out;
    float* scores = (float*)d_ws;   // E floats = 128 KB scratch

    score_kernel<<<E / 4, 256, 0, stream>>>(x, ampli, W, nid, scores);
    softmax_kernel<<<1, 1024, 0, stream>>>(scores, out);
}